// Round 12
// baseline (406.437 us; speedup 1.0000x reference)
//
#include <hip/hip_runtime.h>
#include <hip/hip_bf16.h>

#define H  1024
#define S  32768
#define H2 2048
#define H3 3072

typedef __attribute__((ext_vector_type(8))) short bf16x8;   // 8 bf16 = 4 VGPRs
typedef __attribute__((ext_vector_type(4))) float f32x4;    // MFMA C/D frag

// ---------- fp32 -> bf16 (RNE) helpers ----------
__device__ __forceinline__ unsigned short f2bf(float f) {
    unsigned u = __float_as_uint(f);
    u += 0x7fffu + ((u >> 16) & 1u);
    return (unsigned short)(u >> 16);
}

__device__ __forceinline__ unsigned cvt_pk(float lo, float hi) {
    __hip_bfloat162 h = __float22bfloat162_rn(make_float2(lo, hi));
    unsigned u;
    __builtin_memcpy(&u, &h, 4);
    return u;
}

// fast tanh via v_exp_f32: tanh(x) = 1 - 2/(e^(2x)+1)
__device__ __forceinline__ float tanh_fast(float x) {
    float e = __expf(2.0f * x);
    return 1.0f - 2.0f / (e + 1.0f);
}

// ---------- async global->LDS 16B ----------
__device__ __forceinline__ void async_copy16(const void* g, void* l) {
    __builtin_amdgcn_global_load_lds(
        (const __attribute__((address_space(1))) unsigned int*)g,
        (__attribute__((address_space(3))) unsigned int*)l,
        16, 0, 0);
}

// ---------- fused prep (PROVEN function, verbatim; do_enc=0) ----------
__global__ void prep_all(const float* __restrict__ enc, const float* __restrict__ attn_w,
                         const float* __restrict__ attn_b, const float* __restrict__ hidden,
                         unsigned short* __restrict__ ebf, unsigned short* __restrict__ w2b,
                         float* __restrict__ dvec, float* __restrict__ logits, int do_enc) {
    int b = blockIdx.x;
    if (b < 32) {
        // zero the logits (gemm accumulates via atomicAdd)
        ((float4*)logits)[b * 256 + threadIdx.x] = (float4){0.f, 0.f, 0.f, 0.f};
        return;
    }
    b -= 32;
    if (do_enc) {
        if (b < 32768) {
            size_t idx4 = (size_t)b * 256 + threadIdx.x;       // float4 chunk id
            float4 f = ((const float4*)enc)[idx4];
            ushort4 u;
            u.x = f2bf(f.x); u.y = f2bf(f.y); u.z = f2bf(f.z); u.w = f2bf(f.w);
            ((ushort4*)ebf)[idx4] = u;
            return;
        }
        b -= 32768;
    }
    if (b < 1024) {
        // W2 = attn_w[:, 2048:3072] -> bf16 row-major (N=1024 x K=1024)
        int idx4 = b * 256 + threadIdx.x;
        int n = idx4 >> 8;
        int c = (idx4 & 255) * 4;
        float4 f = *(const float4*)(attn_w + (size_t)n * H3 + H2 + c);
        ushort4 u;
        u.x = f2bf(f.x); u.y = f2bf(f.y); u.z = f2bf(f.z); u.w = f2bf(f.w);
        *(ushort4*)(w2b + (size_t)n * H + c) = u;
        return;
    }
    // dvec[i] = attn_b[i] + sum_{k<2048} hidden[k]*attn_w[i][k]
    b -= 1024;
    int wv = threadIdx.x >> 6, lane = threadIdx.x & 63;
    int row = b * 4 + wv;
    const float* wrow = attn_w + (size_t)row * H3;
    float s = 0.f;
    #pragma unroll
    for (int j = 0; j < 32; ++j) {
        int k = lane + j * 64;
        s += wrow[k] * hidden[k];
    }
    #pragma unroll
    for (int m = 1; m <= 32; m <<= 1) s += __shfl_xor(s, m);
    if (lane == 0) dvec[row] = s + attn_b[row];
}

// ---------- fused gemm v5: 8-wave 512-thread block, small acc, high occupancy ----------
// ROUND-11 POST-MORTEM: explicit double-buffer REGRESSED (127->207us) — the
// compiler can't prove the gload_lds DMA doesn't alias the ds_read buffer, so
// it serializes anyway (matches guide m99/m100), and 2x iterations = 2x fixed
// overhead. REFINED LAW (fits r0/r9/r10): staging throughput ~ 4.6 KB/us PER
// RESIDENT WAVE; resident waves are capped by the UNIFIED VGPR+AGPR file:
//   r10: acc[4][8]=128 AGPR + ~120 arch ~ 250 total -> 2 waves/SIMD -> 7 waves
//   r0:  acc[4][4]=64 AGPR + 60 arch = 124 total   -> 4 waves/SIMD -> 11-16
// FIX: keep staged bytes at 1 GB (128x256 tile halves B redundancy vs r0) but
// use r0's register shape: 8 waves/block (2Mx4N), each wave a 64x64 sub-tile,
// acc[4][4]. BK=32, k-major LDS (r11-refcheck-verified, conflict-free, no
// swizzle), single-buffered, 32 KB LDS. Predicted 16 waves/CU -> ~55-80us.
__global__ __launch_bounds__(512, 4) void attn_gemm_w8(
        const float* __restrict__ enc, const unsigned short* __restrict__ w2b,
        const float* __restrict__ dvec, const float* __restrict__ vw,
        float* __restrict__ logits) {
    __shared__ float Af[32 * 128];               // 16 KB fp32 A, k-major
    __shared__ unsigned short Bt[32 * 256];      // 16 KB bf16 B, k-major

    const int tid = threadIdx.x;
    const int b = blockIdx.x;
    const int rowBlock = (b & 7) * 32 + (b >> 5);   // 0..255 (bijective, XCD-chunked)
    const int colBlock = (b >> 3) & 3;              // 0..3

    const int lane = tid & 63;
    const int wid = tid >> 6;                    // 0..7
    const int wm = wid >> 2, wn = wid & 3;       // 2 x 4 waves; 64x64 per wave
    const int quad = lane >> 4, l16 = lane & 15;

    f32x4 acc[4][4];
    #pragma unroll
    for (int mi = 0; mi < 4; ++mi)
        #pragma unroll
        for (int ni = 0; ni < 4; ++ni)
            acc[mi][ni] = (f32x4){0.f, 0.f, 0.f, 0.f};

    const size_t aRow0 = (size_t)(rowBlock * 128) * H;   // fp32 elements
    const size_t bRow0 = (size_t)(colBlock * 256) * H;   // bf16 elements

    // k-major LDS (free transpose via per-lane gload_lds SOURCE; dest linear):
    //   A chunk c (c=0..1023): row=c&127, k-chunk=c>>7 (8 chunks of 4 fp32)
    //   B chunk c (c=0..1023): row=c&255, k-chunk=c>>8 (4 chunks of 8 bf16)
    // Consumer reads are per-16-lane contiguous -> conflict-free, no swizzle.
    for (int kt = 0; kt < 32; ++kt) {
        const int k0 = kt * 32;

        #pragma unroll
        for (int p = 0; p < 2; ++p) {
            int c = p * 512 + tid;
            async_copy16(enc + aRow0 + (size_t)(c & 127) * H + k0 + ((c >> 7) << 2),
                         (char*)Af + (size_t)c * 16);
        }
        #pragma unroll
        for (int p = 0; p < 2; ++p) {
            int c = p * 512 + tid;
            async_copy16(w2b + bRow0 + (size_t)(c & 255) * H + k0 + ((c >> 8) << 3),
                         (char*)Bt + (size_t)c * 16);
        }

        __syncthreads();   // drains vmcnt(0): tile ready

        bf16x8 af[4], bfr[4];
        #pragma unroll
        for (int i = 0; i < 4; ++i) {
            int ar = wm * 64 + i * 16 + l16;
            float4 f0 = *(const float4*)(Af + ((2 * quad) * 128 + ar) * 4);
            float4 f1 = *(const float4*)(Af + ((2 * quad + 1) * 128 + ar) * 4);
            uint4 u;
            u.x = cvt_pk(f0.x, f0.y);
            u.y = cvt_pk(f0.z, f0.w);
            u.z = cvt_pk(f1.x, f1.y);
            u.w = cvt_pk(f1.z, f1.w);
            __builtin_memcpy(&af[i], &u, 16);
        }
        #pragma unroll
        for (int j = 0; j < 4; ++j) {
            int br = wn * 64 + j * 16 + l16;
            bfr[j] = *(const bf16x8*)((const char*)Bt + ((size_t)quad * 256 + br) * 16);
        }
        #pragma unroll
        for (int mi = 0; mi < 4; ++mi)
            #pragma unroll
            for (int ni = 0; ni < 4; ++ni)
                acc[mi][ni] = __builtin_amdgcn_mfma_f32_16x16x32_bf16(
                    af[mi], bfr[ni], acc[mi][ni], 0, 0, 0);

        __syncthreads();   // tile consumed; next iter may overwrite
    }

    // ---------- epilogue: tanh + v_w-dot + shuffle-reduce + atomic ----------
    float rowsum[4][4];
    #pragma unroll
    for (int mi = 0; mi < 4; ++mi)
        #pragma unroll
        for (int r = 0; r < 4; ++r) rowsum[mi][r] = 0.f;

    #pragma unroll
    for (int ni = 0; ni < 4; ++ni) {
        int colg = colBlock * 256 + wn * 64 + ni * 16 + l16;
        float dv = dvec[colg];
        float vv = vw[colg];
        #pragma unroll
        for (int mi = 0; mi < 4; ++mi)
            #pragma unroll
            for (int r = 0; r < 4; ++r)
                rowsum[mi][r] += tanh_fast(acc[mi][ni][r] + dv) * vv;
    }

    #pragma unroll
    for (int mi = 0; mi < 4; ++mi)
        #pragma unroll
        for (int r = 0; r < 4; ++r) {
            float s = rowsum[mi][r];
            s += __shfl_xor(s, 1);
            s += __shfl_xor(s, 2);
            s += __shfl_xor(s, 4);
            s += __shfl_xor(s, 8);
            rowsum[mi][r] = s;
        }

    if (l16 == 0) {
        int rbase = rowBlock * 128 + wm * 64 + quad * 4;
        #pragma unroll
        for (int mi = 0; mi < 4; ++mi)
            #pragma unroll
            for (int r = 0; r < 4; ++r)
                atomicAdd(&logits[rbase + mi * 16 + r], rowsum[mi][r]);
    }
}

// ---------- softmax over 32768 logits, single workgroup, in-place ----------
__global__ __launch_bounds__(1024) void softmax_k(float* __restrict__ x) {
    __shared__ float red[16];
    const int tid = threadIdx.x;
    const int lane = tid & 63, wv = tid >> 6;

    float v[32];
    float m = -1e30f;
    #pragma unroll
    for (int i = 0; i < 32; ++i) {
        v[i] = x[tid + (i << 10)];
        m = fmaxf(m, v[i]);
    }
    #pragma unroll
    for (int o = 1; o < 64; o <<= 1) m = fmaxf(m, __shfl_xor(m, o));
    if (lane == 0) red[wv] = m;
    __syncthreads();
    #pragma unroll
    for (int i = 0; i < 16; ++i) m = fmaxf(m, red[i]);
    __syncthreads();

    float s = 0.f;
    #pragma unroll
    for (int i = 0; i < 32; ++i) {
        v[i] = expf(v[i] - m);
        s += v[i];
    }
    #pragma unroll
    for (int o = 1; o < 64; o <<= 1) s += __shfl_xor(s, o);
    if (lane == 0) red[wv] = s;
    __syncthreads();
    float tot = 0.f;
    #pragma unroll
    for (int i = 0; i < 16; ++i) tot += red[i];
    float inv = 1.0f / tot;

    #pragma unroll
    for (int i = 0; i < 32; ++i) x[tid + (i << 10)] = v[i] * inv;
}

extern "C" void kernel_launch(void* const* d_in, const int* in_sizes, int n_in,
                              void* d_out, int out_size, void* d_ws, size_t ws_size,
                              hipStream_t stream) {
    const float* hidden = (const float*)d_in[0];   // (1, 2048)
    const float* enc    = (const float*)d_in[1];   // (32768, 1024)
    const float* attn_w = (const float*)d_in[2];   // (1024, 3072)
    const float* attn_b = (const float*)d_in[3];   // (1024,)
    const float* v_w    = (const float*)d_in[4];   // (1, 1024)
    float* out = (float*)d_out;                    // (32768,) fp32

    const size_t W2_BYTES = (size_t)H * H * 2;     // 2 MB
    unsigned short* w2b = (unsigned short*)d_ws;
    float* dvec = (float*)((char*)d_ws + W2_BYTES);

    // prep (proven function, do_enc=0): zero logits + W2->bf16 + dvec
    prep_all<<<dim3(32 + 1024 + 256), dim3(256), 0, stream>>>(
        enc, attn_w, attn_b, hidden, nullptr, w2b, dvec, out, 0);
    attn_gemm_w8<<<dim3(1024), dim3(512), 0, stream>>>(enc, w2b, dvec, v_w, out);
    softmax_k<<<dim3(1), dim3(1024), 0, stream>>>(out);
}

// Round 13
// 357.582 us; speedup vs baseline: 1.1366x; 1.1366x over previous
//
#include <hip/hip_runtime.h>
#include <hip/hip_bf16.h>

#define H  1024
#define S  32768
#define H2 2048
#define H3 3072

typedef __attribute__((ext_vector_type(8))) short bf16x8;   // 8 bf16 = 4 VGPRs
typedef __attribute__((ext_vector_type(4))) float f32x4;    // MFMA C/D frag

// raw barrier / counted vmcnt (T4): full compiler ordering points ("memory")
#define BAR()  asm volatile("s_barrier" ::: "memory")
#define WVM8() asm volatile("s_waitcnt vmcnt(8)" ::: "memory")
#define WVM0() asm volatile("s_waitcnt vmcnt(0)" ::: "memory")

// ---------- fp32 -> bf16 (RNE) helpers ----------
__device__ __forceinline__ unsigned short f2bf(float f) {
    unsigned u = __float_as_uint(f);
    u += 0x7fffu + ((u >> 16) & 1u);
    return (unsigned short)(u >> 16);
}

__device__ __forceinline__ unsigned cvt_pk(float lo, float hi) {
    __hip_bfloat162 h = __float22bfloat162_rn(make_float2(lo, hi));
    unsigned u;
    __builtin_memcpy(&u, &h, 4);
    return u;
}

// fast tanh via v_exp_f32: tanh(x) = 1 - 2/(e^(2x)+1)
__device__ __forceinline__ float tanh_fast(float x) {
    float e = __expf(2.0f * x);
    return 1.0f - 2.0f / (e + 1.0f);
}

// ---------- async global->LDS 16B ----------
__device__ __forceinline__ void async_copy16(const void* g, void* l) {
    __builtin_amdgcn_global_load_lds(
        (const __attribute__((address_space(1))) unsigned int*)g,
        (__attribute__((address_space(3))) unsigned int*)l,
        16, 0, 0);
}

// ---------- fused prep (PROVEN function, verbatim; do_enc=0) ----------
__global__ void prep_all(const float* __restrict__ enc, const float* __restrict__ attn_w,
                         const float* __restrict__ attn_b, const float* __restrict__ hidden,
                         unsigned short* __restrict__ ebf, unsigned short* __restrict__ w2b,
                         float* __restrict__ dvec, float* __restrict__ logits, int do_enc) {
    int b = blockIdx.x;
    if (b < 32) {
        // zero the logits (gemm accumulates via atomicAdd)
        ((float4*)logits)[b * 256 + threadIdx.x] = (float4){0.f, 0.f, 0.f, 0.f};
        return;
    }
    b -= 32;
    if (do_enc) {
        if (b < 32768) {
            size_t idx4 = (size_t)b * 256 + threadIdx.x;       // float4 chunk id
            float4 f = ((const float4*)enc)[idx4];
            ushort4 u;
            u.x = f2bf(f.x); u.y = f2bf(f.y); u.z = f2bf(f.z); u.w = f2bf(f.w);
            ((ushort4*)ebf)[idx4] = u;
            return;
        }
        b -= 32768;
    }
    if (b < 1024) {
        // W2 = attn_w[:, 2048:3072] -> bf16 row-major (N=1024 x K=1024)
        int idx4 = b * 256 + threadIdx.x;
        int n = idx4 >> 8;
        int c = (idx4 & 255) * 4;
        float4 f = *(const float4*)(attn_w + (size_t)n * H3 + H2 + c);
        ushort4 u;
        u.x = f2bf(f.x); u.y = f2bf(f.y); u.z = f2bf(f.z); u.w = f2bf(f.w);
        *(ushort4*)(w2b + (size_t)n * H + c) = u;
        return;
    }
    // dvec[i] = attn_b[i] + sum_{k<2048} hidden[k]*attn_w[i][k]
    b -= 1024;
    int wv = threadIdx.x >> 6, lane = threadIdx.x & 63;
    int row = b * 4 + wv;
    const float* wrow = attn_w + (size_t)row * H3;
    float s = 0.f;
    #pragma unroll
    for (int j = 0; j < 32; ++j) {
        int k = lane + j * 64;
        s += wrow[k] * hidden[k];
    }
    #pragma unroll
    for (int m = 1; m <= 32; m <<= 1) s += __shfl_xor(s, m);
    if (lane == 0) dvec[row] = s + attn_b[row];
}

// ---------- fused gemm v6: counted-vmcnt double-buffer (T4) ----------
// ROUND-12 POST-MORTEM: occupancy 2x'd, gemm WORSE. Model that fits r0-r12:
//   gemm = (blocks/CU x iters) x CP / resident,  CP ~ 1us FIXED + 0.03us/KB.
// The 1us fixed term = the vmcnt(0) drain-tail __syncthreads forces at every
// barrier (each wave eats the slowest-load tail; only 1.6-2.8x cross-block
// overlap hides it). r11's dbuf failed because __syncthreads STILL drains.
// FIX (T4, m218: counted-vs-drain0 = +38-73%): keep next tile's 8 loads in
// flight across the barrier; wait only vmcnt(8) so current tile is complete
// without draining. Raw asm s_barrier ("memory") = compiler ordering point.
// Hazards: buffer overwrite protected by end-of-iter barrier (all waves done
// reading buf[t] before any wave issues tile-t+2 DMA into it); vmcnt is
// per-wave (8 own loads/stage); barriers control-flow-uniform.
// Layouts byte-identical to r11/r12 (refcheck-passed, 0 bank conflicts):
// k-major BK=32, A fp32 [kchunk*128+row], B bf16 [kchunk*256+row], tile
// 128x256, 4 waves 2x2 (wave-tile 64x128), XCD-chunked grid decode.
__global__ __launch_bounds__(256, 2) void attn_gemm_cv(
        const float* __restrict__ enc, const unsigned short* __restrict__ w2b,
        const float* __restrict__ dvec, const float* __restrict__ vw,
        float* __restrict__ logits) {
    __shared__ float Af0[128 * 32];              // 16 KB fp32 A (k-major)
    __shared__ float Af1[128 * 32];              // 16 KB
    __shared__ unsigned short Bt0[256 * 32];     // 16 KB bf16 B (k-major)
    __shared__ unsigned short Bt1[256 * 32];     // 16 KB   -> 64 KB total

    const int tid = threadIdx.x;
    const int b = blockIdx.x;
    const int rowBlock = (b & 7) * 32 + (b >> 5);   // 0..255 (bijective, XCD-chunked)
    const int colBlock = (b >> 3) & 3;              // 0..3

    const int lane = tid & 63;
    const int wv = tid >> 6;
    const int waveM = wv >> 1, waveN = wv & 1;      // wave tile: 64 rows x 128 cols
    const int quad = lane >> 4, l16 = lane & 15;

    f32x4 acc[4][8];
    #pragma unroll
    for (int mi = 0; mi < 4; ++mi)
        #pragma unroll
        for (int ni = 0; ni < 8; ++ni)
            acc[mi][ni] = (f32x4){0.f, 0.f, 0.f, 0.f};

    const size_t aRow0 = (size_t)(rowBlock * 128) * H;   // fp32 elements
    const size_t bRow0 = (size_t)(colBlock * 256) * H;   // bf16 elements

    // STAGE one BK=32 tile (8 gload_lds per thread = 8 vmcnt slots per wave):
    //   A chunk c (0..1023): row=c&127, kchunk=c>>7; B chunk c: row=c&255, kchunk=c>>8
    auto STAGE = [&](float* Ab, unsigned short* Bb, int k0) {
        #pragma unroll
        for (int p = 0; p < 4; ++p) {
            int c = p * 256 + tid;
            async_copy16(enc + aRow0 + (size_t)(c & 127) * H + k0 + ((c >> 7) << 2),
                         (char*)Ab + (size_t)c * 16);
        }
        #pragma unroll
        for (int p = 0; p < 4; ++p) {
            int c = p * 256 + tid;
            async_copy16(w2b + bRow0 + (size_t)(c & 255) * H + k0 + ((c >> 8) << 3),
                         (char*)Bb + (size_t)c * 16);
        }
    };

    // COMPUTE one BK=32 tile (layout r11/r12-refcheck-verified, conflict-free)
    auto COMPUTE = [&](const float* Ab, const unsigned short* Bb) {
        bf16x8 af[4], bfr[8];
        #pragma unroll
        for (int i = 0; i < 4; ++i) {
            int ar = waveM * 64 + i * 16 + l16;
            float4 f0 = *(const float4*)(Ab + ((2 * quad) * 128 + ar) * 4);
            float4 f1 = *(const float4*)(Ab + ((2 * quad + 1) * 128 + ar) * 4);
            uint4 u;
            u.x = cvt_pk(f0.x, f0.y);
            u.y = cvt_pk(f0.z, f0.w);
            u.z = cvt_pk(f1.x, f1.y);
            u.w = cvt_pk(f1.z, f1.w);
            __builtin_memcpy(&af[i], &u, 16);
        }
        #pragma unroll
        for (int j = 0; j < 8; ++j) {
            int br = waveN * 128 + j * 16 + l16;
            bfr[j] = *(const bf16x8*)((const char*)Bb + ((size_t)quad * 256 + br) * 16);
        }
        #pragma unroll
        for (int mi = 0; mi < 4; ++mi)
            #pragma unroll
            for (int ni = 0; ni < 8; ++ni)
                acc[mi][ni] = __builtin_amdgcn_mfma_f32_16x16x32_bf16(
                    af[mi], bfr[ni], acc[mi][ni], 0, 0, 0);
    };

    // ---- counted-vmcnt 2-deep pipeline over 32 BK=32 tiles ----
    STAGE(Af0, Bt0, 0);                    // tile 0 in flight (8)
    #pragma unroll 1
    for (int t = 0; t < 30; t += 2) {
        STAGE(Af1, Bt1, (t + 1) * 32);     // tile t+1 in flight (16 total)
        WVM8();                            // tile t complete; t+1 stays in flight
        BAR();                             // cross-wave: tile t visible to all
        COMPUTE(Af0, Bt0);                 // tile t
        BAR();                             // all waves done reading Af0/Bt0
        STAGE(Af0, Bt0, (t + 2) * 32);     // tile t+2 overwrites buf0 (safe)
        WVM8();                            // tile t+1 complete
        BAR();
        COMPUTE(Af1, Bt1);                 // tile t+1
        BAR();
    }
    STAGE(Af1, Bt1, 31 * 32);              // tile 31 (16 in flight)
    WVM8();                                // tile 30 complete
    BAR();
    COMPUTE(Af0, Bt0);                     // tile 30
    BAR();
    WVM0();                                // tile 31 complete
    BAR();
    COMPUTE(Af1, Bt1);                     // tile 31

    // ---------- epilogue: tanh + v_w-dot + shuffle-reduce + atomic ----------
    float rowsum[4][4];
    #pragma unroll
    for (int mi = 0; mi < 4; ++mi)
        #pragma unroll
        for (int r = 0; r < 4; ++r) rowsum[mi][r] = 0.f;

    #pragma unroll
    for (int ni = 0; ni < 8; ++ni) {
        int colg = colBlock * 256 + waveN * 128 + ni * 16 + l16;
        float dv = dvec[colg];
        float vv = vw[colg];
        #pragma unroll
        for (int mi = 0; mi < 4; ++mi)
            #pragma unroll
            for (int r = 0; r < 4; ++r)
                rowsum[mi][r] += tanh_fast(acc[mi][ni][r] + dv) * vv;
    }

    #pragma unroll
    for (int mi = 0; mi < 4; ++mi)
        #pragma unroll
        for (int r = 0; r < 4; ++r) {
            float s = rowsum[mi][r];
            s += __shfl_xor(s, 1);
            s += __shfl_xor(s, 2);
            s += __shfl_xor(s, 4);
            s += __shfl_xor(s, 8);
            rowsum[mi][r] = s;
        }

    if (l16 == 0) {
        int rbase = rowBlock * 128 + waveM * 64 + quad * 4;
        #pragma unroll
        for (int mi = 0; mi < 4; ++mi)
            #pragma unroll
            for (int r = 0; r < 4; ++r)
                atomicAdd(&logits[rbase + mi * 16 + r], rowsum[mi][r]);
    }
}

// ---------- softmax over 32768 logits, single workgroup, in-place ----------
__global__ __launch_bounds__(1024) void softmax_k(float* __restrict__ x) {
    __shared__ float red[16];
    const int tid = threadIdx.x;
    const int lane = tid & 63, wv = tid >> 6;

    float v[32];
    float m = -1e30f;
    #pragma unroll
    for (int i = 0; i < 32; ++i) {
        v[i] = x[tid + (i << 10)];
        m = fmaxf(m, v[i]);
    }
    #pragma unroll
    for (int o = 1; o < 64; o <<= 1) m = fmaxf(m, __shfl_xor(m, o));
    if (lane == 0) red[wv] = m;
    __syncthreads();
    #pragma unroll
    for (int i = 0; i < 16; ++i) m = fmaxf(m, red[i]);
    __syncthreads();

    float s = 0.f;
    #pragma unroll
    for (int i = 0; i < 32; ++i) {
        v[i] = expf(v[i] - m);
        s += v[i];
    }
    #pragma unroll
    for (int o = 1; o < 64; o <<= 1) s += __shfl_xor(s, o);
    if (lane == 0) red[wv] = s;
    __syncthreads();
    float tot = 0.f;
    #pragma unroll
    for (int i = 0; i < 16; ++i) tot += red[i];
    float inv = 1.0f / tot;

    #pragma unroll
    for (int i = 0; i < 32; ++i) x[tid + (i << 10)] = v[i] * inv;
}

extern "C" void kernel_launch(void* const* d_in, const int* in_sizes, int n_in,
                              void* d_out, int out_size, void* d_ws, size_t ws_size,
                              hipStream_t stream) {
    const float* hidden = (const float*)d_in[0];   // (1, 2048)
    const float* enc    = (const float*)d_in[1];   // (32768, 1024)
    const float* attn_w = (const float*)d_in[2];   // (1024, 3072)
    const float* attn_b = (const float*)d_in[3];   // (1024,)
    const float* v_w    = (const float*)d_in[4];   // (1, 1024)
    float* out = (float*)d_out;                    // (32768,) fp32

    const size_t W2_BYTES = (size_t)H * H * 2;     // 2 MB
    unsigned short* w2b = (unsigned short*)d_ws;
    float* dvec = (float*)((char*)d_ws + W2_BYTES);

    // prep (proven function, do_enc=0): zero logits + W2->bf16 + dvec
    prep_all<<<dim3(32 + 1024 + 256), dim3(256), 0, stream>>>(
        enc, attn_w, attn_b, hidden, nullptr, w2b, dvec, out, 0);
    attn_gemm_cv<<<dim3(1024), dim3(256), 0, stream>>>(enc, w2b, dvec, v_w, out);
    softmax_k<<<dim3(1), dim3(1024), 0, stream>>>(out);
}